// Round 9
// baseline (450.122 us; speedup 1.0000x reference)
//
#include <hip/hip_runtime.h>
#include <hip/hip_cooperative_groups.h>
#include <math.h>

namespace cg = cooperative_groups;

#define NFFT   2048
#define M2     1024
#define LOG2N  11
#define BB     8
#define WW     32
#define MM     16
#define NLAYER 4
#define AST    1032      // row stride (float2) for alpha / G half-spectra

#define PAD(i) ((i) + ((i) >> 5))
#define PADDED_M (M2 + (M2 >> 5))   // 1056

// ---------- fast gelu (exact-erf form, A&S 7.1.26, |err| <= 1.5e-7) ----------
__device__ __forceinline__ float gelu_f(float v) {
    float ax = fabsf(v) * 0.70710678118654752440f;
    float t  = __builtin_amdgcn_rcpf(fmaf(0.3275911f, ax, 1.0f));
    float s  = fmaf(1.061405429f, t, -1.453152027f);
    s = fmaf(s, t, 1.421413741f);
    s = fmaf(s, t, -0.284496736f);
    s = fmaf(s, t, 0.254829592f);
    s = s * t;
    float e  = __expf(-ax * ax);
    float er = fmaf(-s, e, 1.0f);          // erf(|v|/sqrt2)
    er = copysignf(er, v);
    return 0.5f * v * (1.0f + er);
}

// ---------- complex helpers ----------
__device__ __forceinline__ float2 cadd(float2 a, float2 b) { return make_float2(a.x + b.x, a.y + b.y); }
__device__ __forceinline__ float2 csub(float2 a, float2 b) { return make_float2(a.x - b.x, a.y - b.y); }
__device__ __forceinline__ float2 cmul(float2 a, float2 b) {
    return make_float2(fmaf(a.x, b.x, -a.y * b.y), fmaf(a.x, b.y, a.y * b.x));
}
template<int S> __device__ __forceinline__ float2 caddi(float2 a, float2 b) {
    return (S > 0) ? make_float2(a.x - b.y, a.y + b.x) : make_float2(a.x + b.y, a.y - b.x);
}
template<int S> __device__ __forceinline__ float2 csubi(float2 a, float2 b) {
    return (S > 0) ? make_float2(a.x + b.y, a.y - b.x) : make_float2(a.x - b.y, a.y + b.x);
}

template<int S> __device__ __forceinline__ void dft4(float2* a) {
    float2 t0 = cadd(a[0], a[2]), t1 = csub(a[0], a[2]);
    float2 t2 = cadd(a[1], a[3]), t3 = csub(a[1], a[3]);
    a[0] = cadd(t0, t2);
    a[2] = csub(t0, t2);
    a[1] = caddi<S>(t1, t3);
    a[3] = csubi<S>(t1, t3);
}

// ---------- Stockham radix-4 pass on float2 LDS, reg twiddle w1 ----------
template<int LS, int S>
__device__ __forceinline__ void pass_cx(const float2* src, float2* dst, int t, float2 w1f) {
    float2 a[4];
    #pragma unroll
    for (int r = 0; r < 4; ++r) a[r] = src[PAD(t + r * 256)];
    if (LS > 1) {
        float2 w1 = (S > 0) ? make_float2(w1f.x, -w1f.y) : w1f;
        float2 w2 = cmul(w1, w1);
        float2 w3 = cmul(w2, w1);
        a[1] = cmul(a[1], w1);
        a[2] = cmul(a[2], w2);
        a[3] = cmul(a[3], w3);
    }
    dft4<S>(a);
    int s = t & (LS - 1);
    int base = (t / LS) * (4 * LS) + s;
    #pragma unroll
    for (int r = 0; r < 4; ++r) dst[PAD(base + r * LS)] = a[r];
}

// Forward twiddles for the 4 twiddled passes, computed once per thread.
struct Tw { float2 t4, t16, t64, t256; };
__device__ __forceinline__ Tw make_tw(int t) {
    Tw w;
    float sn, cs;
    const float c0 = 6.2831853071795864769f;
    __sincosf(c0 * (float)(t & 3)   * (1.0f / 16.0f),   &sn, &cs); w.t4   = make_float2(cs, -sn);
    __sincosf(c0 * (float)(t & 15)  * (1.0f / 64.0f),   &sn, &cs); w.t16  = make_float2(cs, -sn);
    __sincosf(c0 * (float)(t & 63)  * (1.0f / 256.0f),  &sn, &cs); w.t64  = make_float2(cs, -sn);
    __sincosf(c0 * (float)(t & 255) * (1.0f / 1024.0f), &sn, &cs); w.t256 = make_float2(cs, -sn);
    return w;
}

// 1024-pt FFT: input natural order in A, output in B. act selects worker threads.
// Caller must __syncthreads() before calling.
template<int S>
__device__ __forceinline__ void fft1024_cx(float2* A, float2* B, int t, bool act, const Tw& w) {
    if (act) pass_cx<1,   S>(A, B, t, make_float2(1.0f, 0.0f));
    __syncthreads();
    if (act) pass_cx<4,   S>(B, A, t, w.t4);
    __syncthreads();
    if (act) pass_cx<16,  S>(A, B, t, w.t16);
    __syncthreads();
    if (act) pass_cx<64,  S>(B, A, t, w.t64);
    __syncthreads();
    if (act) pass_cx<256, S>(A, B, t, w.t256);
    __syncthreads();
}

// ---------- fused whole-network kernel (cooperative, grid=256 x 512) ----------
__global__ __launch_bounds__(512) void k_fused(
    const float* __restrict__ pole_re, const float* __restrict__ pole_im,
    const float* __restrict__ res_re,  const float* __restrict__ res_im,
    const float* __restrict__ spec_re, const float* __restrict__ spec_im,
    const float* __restrict__ conv_w,  const float* __restrict__ conv_b,
    const float* __restrict__ tgrid,   const float* __restrict__ x,
    const float* __restrict__ fc0_w,   const float* __restrict__ fc0_b,
    const float* __restrict__ fc1_w,   const float* __restrict__ fc1_b,
    const float* __restrict__ fc2_w,   const float* __restrict__ fc2_b,
    float2* __restrict__ G, float2* __restrict__ alphaA,
    float2* __restrict__ alphaB, float2* __restrict__ hbuf,
    float* __restrict__ out)
{
    cg::grid_group gg = cg::this_grid();
    __shared__ __align__(16) char smem[25104];
    float2* Ycx = (float2*)smem;                 // (M2+2)*8   = 8208 B
    float2* Acx = (float2*)(smem + 8208);        // PADDED_M*8 = 8448 B
    float2* Bcx = (float2*)(smem + 16656);       // PADDED_M*8 = 8448 B
    int t = threadIdx.x;
    int blk = blockIdx.x;
    int tl = t & 255;
    Tw tw = make_tw(tl);
    float dt = tgrid[1] - tgrid[0];
    float fscale = 6.2831853071795864769f / ((float)NFFT * dt);

    // ================= stage 0: genG (waves 0-3) + fc0+rfft (waves 4-7) ======
    if (t < 256) {
        int lane = t & 63;
        int wv = t >> 6;
        for (int uu = 0; uu < 4; ++uu) {
            int u = (blk * 4 + wv) * 4 + uu;          // 0..4095 = (l,o,i)
            int l = u >> 10, r = u & 1023, o = r >> 5, i = r & 31;
            int pb = ((l * WW + i) * WW + o) * MM;
            float cw = conv_w[(l * WW + o) * WW + i];
            float w2r[16];
            float2 acc[16];
            #pragma unroll
            for (int j = 0; j < 16; ++j) {
                float wvv = fscale * (float)(lane + 64 * j);
                w2r[j] = wvv * wvv;
                acc[j] = make_float2(cw, 0.0f);
            }
            #pragma unroll
            for (int mq = 0; mq < 4; ++mq) {
                float4 P_re = *(const float4*)&pole_re[pb + 4 * mq];
                float4 P_im = *(const float4*)&pole_im[pb + 4 * mq];
                float4 R_re = *(const float4*)&res_re [pb + 4 * mq];
                float4 R_im = *(const float4*)&res_im [pb + 4 * mq];
                #pragma unroll
                for (int mm = 0; mm < 4; ++mm) {
                    float Rp = (&P_re.x)[mm], Ip = (&P_im.x)[mm];
                    float Rr = (&R_re.x)[mm], Ir = (&R_im.x)[mm];
                    float b   = fmaf(Rr, Rp, Ir * Ip);      // Re(r * conj(p))
                    float c   = fmaf(Rp, Rp, Ip * Ip);      // |p|^2
                    float dd  = 2.0f * Rp;
                    float dd2 = dd * dd;
                    float add = Rr * dd;
                    float bdd = b * dd;
                    #pragma unroll
                    for (int j = 0; j < 16; ++j) {
                        float uu2 = c - w2r[j];
                        float inv = __builtin_amdgcn_rcpf(fmaf(dd2, w2r[j], uu2 * uu2));
                        acc[j].x = fmaf(fmaf(add, w2r[j], b * uu2), -inv, acc[j].x);
                        acc[j].y = fmaf(fmaf(Rr, uu2, -bdd), inv, acc[j].y);  // *w deferred
                    }
                }
            }
            #pragma unroll
            for (int j = 0; j < 16; ++j)
                acc[j].y *= fscale * (float)(lane + 64 * j);
            if (lane < MM) {               // spectral-conv fold: bins k = lane < 16
                if (lane) {
                    acc[0].x += spec_re[pb + lane];
                    acc[0].y += spec_im[pb + lane];
                } else {
                    acc[0].x += spec_re[pb];   // DC stays real
                }
            }
            float2* grow = G + (size_t)((l * WW + o) * WW + i) * AST;
            #pragma unroll
            for (int j = 0; j < 16; ++j) grow[lane + 64 * j] = acc[j];
            if (lane == 0) {               // Nyquist: Re(H(w_nyq)), w negative
                float wn = -fscale * (float)M2;
                float accn = cw;
                #pragma unroll
                for (int mq = 0; mq < 4; ++mq) {
                    float4 P_re = *(const float4*)&pole_re[pb + 4 * mq];
                    float4 P_im = *(const float4*)&pole_im[pb + 4 * mq];
                    float4 R_re = *(const float4*)&res_re [pb + 4 * mq];
                    float4 R_im = *(const float4*)&res_im [pb + 4 * mq];
                    #pragma unroll
                    for (int mm = 0; mm < 4; ++mm) {
                        float Rp = (&P_re.x)[mm], Ip = (&P_im.x)[mm];
                        float Rr = (&R_re.x)[mm], Ir = (&R_im.x)[mm];
                        float e   = wn - Ip;
                        float num = fmaf(Ir, e, -(Rr * Rp));
                        float den = fmaf(e, e, Rp * Rp);
                        accn += num * __builtin_amdgcn_rcpf(den);
                    }
                }
                grow[M2] = make_float2(accn, 0.0f);
            }
        }
    } else {
        // fc0 + rfft staging for row = blk
        int b = blk >> 5, w = blk & 31;
        float w0 = fc0_w[2 * w], w1 = fc0_w[2 * w + 1], b0 = fc0_b[w];
        const float2* x2 = (const float2*)(x + (size_t)b * NFFT);
        #pragma unroll
        for (int j = 0; j < 4; ++j) {
            int n = tl + j * 256;
            float2 xv = x2[n];
            float g0 = (float)(2 * n)     * (1.0f / 2047.0f);
            float g1 = (float)(2 * n + 1) * (1.0f / 2047.0f);
            Acx[PAD(n)] = make_float2(gelu_f(fmaf(w0, xv.x, fmaf(w1, g0, b0))),
                                      gelu_f(fmaf(w0, xv.y, fmaf(w1, g1, b0))));
        }
    }
    __syncthreads();
    fft1024_cx<-1>(Acx, Bcx, tl, t >= 256, tw);
    if (t >= 256) {
        float2* arow = alphaA + (size_t)blk * AST;
        #pragma unroll
        for (int j = 0; j < 4; ++j) {
            int k  = tl + j * 256;
            int mk = (M2 - k) & (M2 - 1);
            float2 Zk  = Bcx[PAD(k)];
            float2 Zmk = Bcx[PAD(mk)];
            float2 A  = make_float2(0.5f * (Zk.x + Zmk.x), 0.5f * (Zk.y - Zmk.y));
            float2 Bv = make_float2(0.5f * (Zk.y + Zmk.y), -0.5f * (Zk.x - Zmk.x));
            float ph = (3.1415926535897932385f / (float)M2) * (float)k;
            float sn, cs;
            __sincosf(ph, &sn, &cs);
            float2 e = make_float2(cs, -sn);
            float2 X = cadd(A, cmul(Bv, e));
            arow[k] = X;
            if (k == 0) arow[M2] = make_float2(A.x - Bv.x, 0.0f);
        }
    }
    __threadfence();
    gg.sync();

    // ================= layers 0..3 ==========================================
    const float2* acur = alphaA;
    float2* anxt = alphaB;
    int b = blk >> 5, o = blk & 31;
    for (int layer = 0; layer < NLAYER; ++layer) {
        const bool last = (layer == NLAYER - 1);
        const float2* abase = acur + (size_t)(b * WW) * AST;
        const float2* gbase = G + (size_t)((layer * WW + o) * WW) * AST;

        // einsum: thread t owns bins 2t, 2t+1 -> float4 loads
        float2 acc0 = make_float2(0.0f, 0.0f);
        float2 acc1 = make_float2(0.0f, 0.0f);
        #pragma unroll 4
        for (int i = 0; i < 32; ++i) {
            const float4* ar = (const float4*)(abase + (size_t)i * AST);
            const float4* gr = (const float4*)(gbase + (size_t)i * AST);
            float4 av = ar[t];
            float4 gv = gr[t];
            acc0.x = fmaf(av.x, gv.x, fmaf(-av.y, gv.y, acc0.x));
            acc0.y = fmaf(av.x, gv.y, fmaf( av.y, gv.x, acc0.y));
            acc1.x = fmaf(av.z, gv.z, fmaf(-av.w, gv.w, acc1.x));
            acc1.y = fmaf(av.z, gv.w, fmaf( av.w, gv.z, acc1.y));
        }
        // Nyquist: real dot over i, wave-0 shuffle reduce
        if (t < 64) {
            float p = 0.0f;
            if (t < 32)
                p = abase[(size_t)t * AST + M2].x * gbase[(size_t)t * AST + M2].x;
            #pragma unroll
            for (int off = 16; off >= 1; off >>= 1) p += __shfl_xor(p, off);
            if (t == 0) Ycx[M2] = make_float2(p, 0.0f);
        }
        if (t == 0) acc0.x += (float)NFFT * conv_b[layer * WW + o];
        ((float4*)Ycx)[t] = make_float4(acc0.x, acc0.y, acc1.x, acc1.y);
        __syncthreads();

        // irfft pack: Z[k] = A + iB from X[k], X[M2-k]
        #pragma unroll
        for (int j = 0; j < 2; ++j) {
            int k = t + j * 512;
            float2 Xk = Ycx[k];
            float2 Xm = Ycx[M2 - k];
            float2 A = make_float2(0.5f * (Xk.x + Xm.x), 0.5f * (Xk.y - Xm.y));
            float2 u = make_float2(Xk.x - Xm.x, Xk.y + Xm.y);
            float ph = (3.1415926535897932385f / (float)M2) * (float)k;
            float sn, cs;
            __sincosf(ph, &sn, &cs);
            float2 e = make_float2(cs, sn);            // e^{+i*2pi*k/N}
            float2 Bv = cmul(u, e);
            Acx[PAD(k)] = make_float2(A.x - 0.5f * Bv.y, A.y + 0.5f * Bv.x);
        }
        __syncthreads();
        fft1024_cx<1>(Acx, Bcx, tl, t < 256, tw);      // inverse -> B
        const float invM = 1.0f / (float)M2;
        if (last) {
            #pragma unroll
            for (int j = 0; j < 2; ++j) {
                int n = t + j * 512;
                float2 z = Bcx[PAD(n)];
                hbuf[(size_t)blk * M2 + n] = make_float2(gelu_f(z.x * invM), gelu_f(z.y * invM));
            }
        } else {
            #pragma unroll
            for (int j = 0; j < 2; ++j) {
                int n = t + j * 512;
                float2 z = Bcx[PAD(n)];
                Acx[PAD(n)] = make_float2(gelu_f(z.x * invM), gelu_f(z.y * invM));
            }
            __syncthreads();
            fft1024_cx<-1>(Acx, Bcx, tl, t < 256, tw);
            float2* arow = anxt + (size_t)blk * AST;
            #pragma unroll
            for (int j = 0; j < 2; ++j) {
                int k  = t + j * 512;
                int mk = (M2 - k) & (M2 - 1);
                float2 Zk  = Bcx[PAD(k)];
                float2 Zmk = Bcx[PAD(mk)];
                float2 A  = make_float2(0.5f * (Zk.x + Zmk.x), 0.5f * (Zk.y - Zmk.y));
                float2 Bv = make_float2(0.5f * (Zk.y + Zmk.y), -0.5f * (Zk.x - Zmk.x));
                float ph = (3.1415926535897932385f / (float)M2) * (float)k;
                float sn, cs;
                __sincosf(ph, &sn, &cs);
                float2 e = make_float2(cs, -sn);       // e^{-i*2pi*k/N}
                float2 X = cadd(A, cmul(Bv, e));
                arow[k] = X;
                if (k == 0) arow[M2] = make_float2(A.x - Bv.x, 0.0f);
            }
        }
        __threadfence();
        gg.sync();
        float2* tmp = (float2*)acur; acur = anxt; anxt = tmp;
    }

    // ================= head =================================================
    {
        float* s_w1  = (float*)smem;                    // 16384 B
        float* s_b1  = (float*)(smem + 16384);          // 512 B
        float* s_w2  = (float*)(smem + 16896);          // 512 B
        float* s_prt = (float*)(smem + 17408);          // 8*64*4 = 2048 B
        for (int j = t; j < 128 * 32; j += 512) s_w1[j] = fc1_w[j];
        if (t < 128) { s_b1[t] = fc1_b[t]; s_w2[t] = fc2_w[t]; }
        __syncthreads();
        int wv = t >> 6, ln = t & 63;
        int pos = blk * 64 + ln;                  // b*2048 + l
        int hb = pos >> LOG2N, hl = pos & (NFFT - 1);
        const float* h = (const float*)hbuf;
        float hreg[32];
        #pragma unroll
        for (int w = 0; w < 32; ++w) hreg[w] = h[(hb * WW + w) * NFFT + hl];
        float acc = 0.0f;
        int n0 = wv * 16;
        for (int n = n0; n < n0 + 16; ++n) {
            float a = s_b1[n];
            #pragma unroll
            for (int w = 0; w < 32; w += 4) {
                float4 ww = *(const float4*)&s_w1[n * 32 + w];
                a = fmaf(ww.x, hreg[w],     a);
                a = fmaf(ww.y, hreg[w + 1], a);
                a = fmaf(ww.z, hreg[w + 2], a);
                a = fmaf(ww.w, hreg[w + 3], a);
            }
            acc = fmaf(s_w2[n], gelu_f(a), acc);
        }
        s_prt[wv * 64 + ln] = acc;
        __syncthreads();
        if (t < 64) {
            float r = fc2_b[0];
            #pragma unroll
            for (int q = 0; q < 8; ++q) r += s_prt[q * 64 + t];
            out[blk * 64 + t] = r;
        }
    }
}

extern "C" void kernel_launch(void* const* d_in, const int* in_sizes, int n_in,
                              void* d_out, int out_size, void* d_ws, size_t ws_size,
                              hipStream_t stream)
{
    const float* x       = (const float*)d_in[0];
    const float* tg      = (const float*)d_in[1];
    const float* fc0_w   = (const float*)d_in[2];
    const float* fc0_b   = (const float*)d_in[3];
    const float* pole_re = (const float*)d_in[4];
    const float* pole_im = (const float*)d_in[5];
    const float* res_re  = (const float*)d_in[6];
    const float* res_im  = (const float*)d_in[7];
    const float* spec_re = (const float*)d_in[8];
    const float* spec_im = (const float*)d_in[9];
    const float* conv_w  = (const float*)d_in[10];
    const float* conv_b  = (const float*)d_in[11];
    const float* fc1_w   = (const float*)d_in[12];
    const float* fc1_b   = (const float*)d_in[13];
    const float* fc2_w   = (const float*)d_in[14];
    const float* fc2_b   = (const float*)d_in[15];
    float* out = (float*)d_out;

    char* ws = (char*)d_ws;
    const size_t plane = (size_t)(BB * WW) * AST * sizeof(float2);   // 2.11 MiB
    float2* alphaA = (float2*)ws;
    float2* alphaB = (float2*)(ws + plane);
    float2* hbuf   = (float2*)(ws + 2 * plane);                      // 2 MiB
    float2* Gbuf   = (float2*)(ws + 3 * plane);                      // 33.8 MiB

    void* args[] = {
        (void*)&pole_re, (void*)&pole_im, (void*)&res_re, (void*)&res_im,
        (void*)&spec_re, (void*)&spec_im, (void*)&conv_w, (void*)&conv_b,
        (void*)&tg, (void*)&x, (void*)&fc0_w, (void*)&fc0_b,
        (void*)&fc1_w, (void*)&fc1_b, (void*)&fc2_w, (void*)&fc2_b,
        (void*)&Gbuf, (void*)&alphaA, (void*)&alphaB, (void*)&hbuf,
        (void*)&out
    };
    hipLaunchCooperativeKernel((const void*)k_fused, dim3(BB * WW), dim3(512),
                               args, 0, stream);
}

// Round 10
// 105.984 us; speedup vs baseline: 4.2471x; 4.2471x over previous
//
#include <hip/hip_runtime.h>
#include <math.h>

#define NFFT   2048
#define M2     1024
#define LOG2N  11
#define BB     8
#define WW     32
#define MM     16
#define NLAYER 4
#define AST    1032      // row stride (float2) for alpha / G half-spectra

// Padded LDS index (element-granular) for 1024-pt FFT arrays
#define PAD(i) ((i) + ((i) >> 5))
#define PADDED_M (M2 + (M2 >> 5))   // 1056

// ---------- fast gelu (exact-erf form, A&S 7.1.26, |err| <= 1.5e-7) ----------
__device__ __forceinline__ float gelu_f(float v) {
    float ax = fabsf(v) * 0.70710678118654752440f;
    float t  = __builtin_amdgcn_rcpf(fmaf(0.3275911f, ax, 1.0f));
    float s  = fmaf(1.061405429f, t, -1.453152027f);
    s = fmaf(s, t, 1.421413741f);
    s = fmaf(s, t, -0.284496736f);
    s = fmaf(s, t, 0.254829592f);
    s = s * t;
    float e  = __expf(-ax * ax);
    float er = fmaf(-s, e, 1.0f);          // erf(|v|/sqrt2)
    er = copysignf(er, v);
    return 0.5f * v * (1.0f + er);
}

// ---------- complex helpers ----------
__device__ __forceinline__ float2 cadd(float2 a, float2 b) { return make_float2(a.x + b.x, a.y + b.y); }
__device__ __forceinline__ float2 csub(float2 a, float2 b) { return make_float2(a.x - b.x, a.y - b.y); }
__device__ __forceinline__ float2 cmul(float2 a, float2 b) {
    return make_float2(fmaf(a.x, b.x, -a.y * b.y), fmaf(a.x, b.y, a.y * b.x));
}
template<int S> __device__ __forceinline__ float2 caddi(float2 a, float2 b) {
    return (S > 0) ? make_float2(a.x - b.y, a.y + b.x) : make_float2(a.x + b.y, a.y - b.x);
}
template<int S> __device__ __forceinline__ float2 csubi(float2 a, float2 b) {
    return (S > 0) ? make_float2(a.x + b.y, a.y - b.x) : make_float2(a.x - b.y, a.y + b.x);
}

template<int S> __device__ __forceinline__ void dft4(float2* a) {
    float2 t0 = cadd(a[0], a[2]), t1 = csub(a[0], a[2]);
    float2 t2 = cadd(a[1], a[3]), t3 = csub(a[1], a[3]);
    a[0] = cadd(t0, t2);
    a[2] = csub(t0, t2);
    a[1] = caddi<S>(t1, t3);
    a[3] = csubi<S>(t1, t3);
}

// ---------- Stockham radix-4 pass on float2 LDS, reg twiddle w1 ----------
template<int LS, int S>
__device__ __forceinline__ void pass_cx(const float2* src, float2* dst, int t, float2 w1f) {
    float2 a[4];
    #pragma unroll
    for (int r = 0; r < 4; ++r) a[r] = src[PAD(t + r * 256)];
    if (LS > 1) {
        float2 w1 = (S > 0) ? make_float2(w1f.x, -w1f.y) : w1f;
        float2 w2 = cmul(w1, w1);
        float2 w3 = cmul(w2, w1);
        a[1] = cmul(a[1], w1);
        a[2] = cmul(a[2], w2);
        a[3] = cmul(a[3], w3);
    }
    dft4<S>(a);
    int s = t & (LS - 1);
    int base = (t / LS) * (4 * LS) + s;
    #pragma unroll
    for (int r = 0; r < 4; ++r) dst[PAD(base + r * LS)] = a[r];
}

// ifft first pass (LS=1, S=+1): reads packed Z directly from Ycx (unpadded),
// performing the irfft Hermitian pack in registers. Saves a barrier + LDS trip.
__device__ __forceinline__ void ifft_pass1_pack(const float2* Ycx, float2* dst, int t) {
    float2 a[4];
    #pragma unroll
    for (int r = 0; r < 4; ++r) {
        int k = t + r * 256;
        float2 Xk = Ycx[k];
        float2 Xm = Ycx[M2 - k];            // k=0 -> Ycx[M2] (Nyquist slot)
        float2 A = make_float2(0.5f * (Xk.x + Xm.x), 0.5f * (Xk.y - Xm.y));
        float2 u = make_float2(Xk.x - Xm.x, Xk.y + Xm.y);
        float ph = (3.1415926535897932385f / (float)M2) * (float)k;
        float sn, cs;
        __sincosf(ph, &sn, &cs);
        float2 Bv = cmul(u, make_float2(cs, sn));    // e^{+i*2pi*k/N}
        a[r] = make_float2(A.x - 0.5f * Bv.y, A.y + 0.5f * Bv.x);
    }
    dft4<1>(a);
    int base = t * 4;
    #pragma unroll
    for (int r = 0; r < 4; ++r) dst[PAD(base + r)] = a[r];
}

// forward first pass (LS=1, S=-1): reads gelu(z*invM) from padded src.
__device__ __forceinline__ void fwd_pass1_gelu(const float2* src, float2* dst, int t, float invM) {
    float2 a[4];
    #pragma unroll
    for (int r = 0; r < 4; ++r) {
        float2 z = src[PAD(t + r * 256)];
        a[r] = make_float2(gelu_f(z.x * invM), gelu_f(z.y * invM));
    }
    dft4<-1>(a);
    int base = t * 4;
    #pragma unroll
    for (int r = 0; r < 4; ++r) dst[PAD(base + r)] = a[r];
}

// Forward twiddles for the 4 twiddled passes, computed once per thread (t<256).
struct Tw { float2 t4, t16, t64, t256; };
__device__ __forceinline__ Tw make_tw(int t) {
    Tw w;
    float sn, cs;
    const float c0 = 6.2831853071795864769f;
    __sincosf(c0 * (float)(t & 3)   * (1.0f / 16.0f),   &sn, &cs); w.t4   = make_float2(cs, -sn);
    __sincosf(c0 * (float)(t & 15)  * (1.0f / 64.0f),   &sn, &cs); w.t16  = make_float2(cs, -sn);
    __sincosf(c0 * (float)(t & 63)  * (1.0f / 256.0f),  &sn, &cs); w.t64  = make_float2(cs, -sn);
    __sincosf(c0 * (float)(t & 255) * (1.0f / 1024.0f), &sn, &cs); w.t256 = make_float2(cs, -sn);
    return w;
}

// 1024-pt FFT: input natural order in A, output in B. act = worker threads.
// Caller must __syncthreads() before calling.
template<int S>
__device__ __forceinline__ void fft1024_cx(float2* A, float2* B, int t, bool act, const Tw& w) {
    if (act) pass_cx<1,   S>(A, B, t, make_float2(1.0f, 0.0f));
    __syncthreads();
    if (act) pass_cx<4,   S>(B, A, t, w.t4);
    __syncthreads();
    if (act) pass_cx<16,  S>(A, B, t, w.t16);
    __syncthreads();
    if (act) pass_cx<64,  S>(B, A, t, w.t64);
    __syncthreads();
    if (act) pass_cx<256, S>(A, B, t, w.t256);
    __syncthreads();
}

// ---------- K_genG_fc0 (round-8 proven version) ----------
__global__ __launch_bounds__(256) void k_genG_fc0(
    const float* __restrict__ pole_re, const float* __restrict__ pole_im,
    const float* __restrict__ res_re,  const float* __restrict__ res_im,
    const float* __restrict__ spec_re, const float* __restrict__ spec_im,
    const float* __restrict__ conv_w,  const float* __restrict__ tgrid,
    const float* __restrict__ x,       const float* __restrict__ fc0_w,
    const float* __restrict__ fc0_b,
    float2* __restrict__ G, float2* __restrict__ alpha)
{
    __shared__ float2 Acx[PADDED_M], Bcx[PADDED_M];
    int t = threadIdx.x;
    int blk = blockIdx.x;
    float dt = tgrid[1] - tgrid[0];
    float fscale = 6.2831853071795864769f / ((float)NFFT * dt);

    if (blk < NLAYER * WW * WW / 4) {
        // ---- genG: one (l,o,i) unit per wave ----
        int lane = t & 63;
        int u = blk * 4 + (t >> 6);
        int l = u >> 10, r = u & 1023, o = r >> 5, i = r & 31;
        int pb = ((l * WW + i) * WW + o) * MM;
        float cw = conv_w[(l * WW + o) * WW + i];
        float w2r[16];
        float2 acc[16];
        #pragma unroll
        for (int j = 0; j < 16; ++j) {
            float wv = fscale * (float)(lane + 64 * j);
            w2r[j] = wv * wv;
            acc[j] = make_float2(cw, 0.0f);
        }
        #pragma unroll
        for (int mq = 0; mq < 4; ++mq) {
            float4 P_re = *(const float4*)&pole_re[pb + 4 * mq];
            float4 P_im = *(const float4*)&pole_im[pb + 4 * mq];
            float4 R_re = *(const float4*)&res_re [pb + 4 * mq];
            float4 R_im = *(const float4*)&res_im [pb + 4 * mq];
            #pragma unroll
            for (int mm = 0; mm < 4; ++mm) {
                float Rp = (&P_re.x)[mm], Ip = (&P_im.x)[mm];
                float Rr = (&R_re.x)[mm], Ir = (&R_im.x)[mm];
                float b   = fmaf(Rr, Rp, Ir * Ip);      // Re(r * conj(p))
                float c   = fmaf(Rp, Rp, Ip * Ip);      // |p|^2
                float dd  = 2.0f * Rp;
                float dd2 = dd * dd;
                float add = Rr * dd;
                float bdd = b * dd;
                #pragma unroll
                for (int j = 0; j < 16; ++j) {
                    float uu  = c - w2r[j];
                    float inv = __builtin_amdgcn_rcpf(fmaf(dd2, w2r[j], uu * uu));
                    acc[j].x = fmaf(fmaf(add, w2r[j], b * uu), -inv, acc[j].x);
                    acc[j].y = fmaf(fmaf(Rr, uu, -bdd), inv, acc[j].y);  // *wv deferred
                }
            }
        }
        #pragma unroll
        for (int j = 0; j < 16; ++j)
            acc[j].y *= fscale * (float)(lane + 64 * j);
        if (lane < MM) {               // spectral-conv fold: bins k = lane < 16
            if (lane) {
                acc[0].x += spec_re[pb + lane];
                acc[0].y += spec_im[pb + lane];
            } else {
                acc[0].x += spec_re[pb];   // DC stays real
            }
        }
        float2* grow = G + (size_t)((l * WW + o) * WW + i) * AST;
        #pragma unroll
        for (int j = 0; j < 16; ++j) grow[lane + 64 * j] = acc[j];
        if (lane == 0) {               // Nyquist: Re(H(w_nyq)), w negative
            float wn = -fscale * (float)M2;
            float accn = cw;
            #pragma unroll
            for (int mq = 0; mq < 4; ++mq) {
                float4 P_re = *(const float4*)&pole_re[pb + 4 * mq];
                float4 P_im = *(const float4*)&pole_im[pb + 4 * mq];
                float4 R_re = *(const float4*)&res_re [pb + 4 * mq];
                float4 R_im = *(const float4*)&res_im [pb + 4 * mq];
                #pragma unroll
                for (int mm = 0; mm < 4; ++mm) {
                    float Rp = (&P_re.x)[mm], Ip = (&P_im.x)[mm];
                    float Rr = (&R_re.x)[mm], Ir = (&R_im.x)[mm];
                    float e   = wn - Ip;
                    float num = fmaf(Ir, e, -(Rr * Rp));
                    float den = fmaf(e, e, Rp * Rp);
                    accn += num * __builtin_amdgcn_rcpf(den);
                }
            }
            grow[M2] = make_float2(accn, 0.0f);
        }
    } else {
        // ---- fc0 + rfft path ----
        int row = blk - NLAYER * WW * WW / 4;   // b*32 + w
        int b = row >> 5, w = row & 31;
        float w0 = fc0_w[2 * w], w1 = fc0_w[2 * w + 1], b0 = fc0_b[w];
        Tw tw = make_tw(t);
        const float2* x2 = (const float2*)(x + (size_t)b * NFFT);
        #pragma unroll
        for (int j = 0; j < 4; ++j) {
            int n = t + j * 256;
            float2 xv = x2[n];
            float g0 = (float)(2 * n)     * (1.0f / 2047.0f);
            float g1 = (float)(2 * n + 1) * (1.0f / 2047.0f);
            float v0 = gelu_f(fmaf(w0, xv.x, fmaf(w1, g0, b0)));
            float v1 = gelu_f(fmaf(w0, xv.y, fmaf(w1, g1, b0)));
            Acx[PAD(n)] = make_float2(v0, v1);   // z[n] = h[2n] + i h[2n+1]
        }
        __syncthreads();
        fft1024_cx<-1>(Acx, Bcx, t, true, tw);
        float2* arow = alpha + (size_t)row * AST;
        #pragma unroll
        for (int j = 0; j < 4; ++j) {
            int k  = t + j * 256;
            int mk = (M2 - k) & (M2 - 1);
            float2 Zk  = Bcx[PAD(k)];
            float2 Zmk = Bcx[PAD(mk)];
            float2 A  = make_float2(0.5f * (Zk.x + Zmk.x), 0.5f * (Zk.y - Zmk.y));
            float2 Bv = make_float2(0.5f * (Zk.y + Zmk.y), -0.5f * (Zk.x - Zmk.x));
            float ph = (3.1415926535897932385f / (float)M2) * (float)k;
            float sn, cs;
            __sincosf(ph, &sn, &cs);
            float2 e = make_float2(cs, -sn);           // e^{-i*2pi*k/N}
            float2 X = cadd(A, cmul(Bv, e));
            arow[k] = X;
            if (k == 0) arow[M2] = make_float2(A.x - Bv.x, 0.0f);
        }
    }
}

// ---------- K_layer: einsum over i + irfft + gelu + (rfft | store h) ----------
// block = (b,o) row, 512 threads. Yh[k] = sum_i alpha[b,i,k]*G[l,o,i,k]
// FFT chains have the irfft-pack and gelu fused into their first passes
// (removes 2 barriers + 16 LDS ops/thread vs round 8).
template<bool LAST>
__global__ __launch_bounds__(512) void k_apply_fft(
    const float2* __restrict__ alpha, const float2* __restrict__ G,
    const float* __restrict__ conv_b, float2* __restrict__ alpha_next,
    float2* __restrict__ hout, int layer)
{
    __shared__ __align__(16) float2 Ycx[M2 + 2];
    __shared__ float2 Acx[PADDED_M], Bcx[PADDED_M];
    int t = threadIdx.x;
    int row = blockIdx.x;            // b*32 + o
    int b = row >> 5, o = row & 31;
    const float2* abase = alpha + (size_t)(b * WW) * AST;
    const float2* gbase = G + (size_t)((layer * WW + o) * WW) * AST;
    const bool act = (t < 256);
    Tw tw;
    if (act) tw = make_tw(t);

    // einsum: thread t owns bins 2t, 2t+1 -> float4 loads (16B)
    float2 acc0 = make_float2(0.0f, 0.0f);
    float2 acc1 = make_float2(0.0f, 0.0f);
    #pragma unroll 8
    for (int i = 0; i < 32; ++i) {
        const float4* ar = (const float4*)(abase + (size_t)i * AST);
        const float4* gr = (const float4*)(gbase + (size_t)i * AST);
        float4 av = ar[t];
        float4 gv = gr[t];
        acc0.x = fmaf(av.x, gv.x, fmaf(-av.y, gv.y, acc0.x));
        acc0.y = fmaf(av.x, gv.y, fmaf( av.y, gv.x, acc0.y));
        acc1.x = fmaf(av.z, gv.z, fmaf(-av.w, gv.w, acc1.x));
        acc1.y = fmaf(av.z, gv.w, fmaf( av.w, gv.z, acc1.y));
    }
    // Nyquist: real dot over i, wave-0 shuffle reduce
    if (t < 64) {
        float p = 0.0f;
        if (t < 32)
            p = abase[(size_t)t * AST + M2].x * gbase[(size_t)t * AST + M2].x;
        #pragma unroll
        for (int off = 16; off >= 1; off >>= 1) p += __shfl_xor(p, off);
        if (t == 0) Ycx[M2] = make_float2(p, 0.0f);
    }
    if (t == 0) acc0.x += (float)NFFT * conv_b[layer * WW + o];
    ((float4*)Ycx)[t] = make_float4(acc0.x, acc0.y, acc1.x, acc1.y);
    __syncthreads();

    // inverse FFT with inline Hermitian pack (p1: Ycx -> Acx; ends in Acx)
    if (act) ifft_pass1_pack(Ycx, Acx, t);
    __syncthreads();
    if (act) pass_cx<4,   1>(Acx, Bcx, t, tw.t4);
    __syncthreads();
    if (act) pass_cx<16,  1>(Bcx, Acx, t, tw.t16);
    __syncthreads();
    if (act) pass_cx<64,  1>(Acx, Bcx, t, tw.t64);
    __syncthreads();
    if (act) pass_cx<256, 1>(Bcx, Acx, t, tw.t256);
    __syncthreads();

    const float invM = 1.0f / (float)M2;
    if (LAST) {
        #pragma unroll
        for (int j = 0; j < 2; ++j) {
            int n = t + j * 512;
            float2 z = Acx[PAD(n)];
            hout[(size_t)row * M2 + n] = make_float2(gelu_f(z.x * invM), gelu_f(z.y * invM));
        }
    } else {
        // forward FFT with inline gelu (p1: Acx -> Bcx; ends in Bcx)
        if (act) fwd_pass1_gelu(Acx, Bcx, t, invM);
        __syncthreads();
        if (act) pass_cx<4,   -1>(Bcx, Acx, t, tw.t4);
        __syncthreads();
        if (act) pass_cx<16,  -1>(Acx, Bcx, t, tw.t16);
        __syncthreads();
        if (act) pass_cx<64,  -1>(Bcx, Acx, t, tw.t64);
        __syncthreads();
        if (act) pass_cx<256, -1>(Acx, Bcx, t, tw.t256);
        __syncthreads();
        float2* arow = alpha_next + (size_t)row * AST;
        #pragma unroll
        for (int j = 0; j < 2; ++j) {
            int k  = t + j * 512;
            int mk = (M2 - k) & (M2 - 1);
            float2 Zk  = Bcx[PAD(k)];
            float2 Zmk = Bcx[PAD(mk)];
            float2 A  = make_float2(0.5f * (Zk.x + Zmk.x), 0.5f * (Zk.y - Zmk.y));
            float2 Bv = make_float2(0.5f * (Zk.y + Zmk.y), -0.5f * (Zk.x - Zmk.x));
            float ph = (3.1415926535897932385f / (float)M2) * (float)k;
            float sn, cs;
            __sincosf(ph, &sn, &cs);
            float2 e = make_float2(cs, -sn);       // e^{-i*2pi*k/N}
            float2 X = cadd(A, cmul(Bv, e));
            arow[k] = X;
            if (k == 0) arow[M2] = make_float2(A.x - Bv.x, 0.0f);
        }
    }
}

// ---------- K5: head ----------
__global__ __launch_bounds__(256) void k_head(
    const float* __restrict__ h, const float* __restrict__ fc1_w,
    const float* __restrict__ fc1_b, const float* __restrict__ fc2_w,
    const float* __restrict__ fc2_b, float* __restrict__ out)
{
    __shared__ float s_w1[128 * 32];
    __shared__ float s_b1[128];
    __shared__ float s_w2[128];
    __shared__ float s_part[4][64];
    int t = threadIdx.x;
    for (int j = t; j < 128 * 32; j += 256) s_w1[j] = fc1_w[j];
    if (t < 128) { s_b1[t] = fc1_b[t]; s_w2[t] = fc2_w[t]; }
    __syncthreads();
    int wv  = t >> 6;                       // wave id = n-group
    int ln  = t & 63;
    int pos = blockIdx.x * 64 + ln;         // b*2048 + l
    int b = pos >> LOG2N, l = pos & (NFFT - 1);
    float hreg[32];
    #pragma unroll
    for (int w = 0; w < 32; ++w) hreg[w] = h[(b * WW + w) * NFFT + l];
    float acc = 0.0f;
    int n0 = wv * 32;
    for (int n = n0; n < n0 + 32; ++n) {
        float a = s_b1[n];
        #pragma unroll
        for (int w = 0; w < 32; w += 4) {
            float4 ww = *(const float4*)&s_w1[n * 32 + w];
            a = fmaf(ww.x, hreg[w],     a);
            a = fmaf(ww.y, hreg[w + 1], a);
            a = fmaf(ww.z, hreg[w + 2], a);
            a = fmaf(ww.w, hreg[w + 3], a);
        }
        acc = fmaf(s_w2[n], gelu_f(a), acc);
    }
    s_part[wv][ln] = acc;
    __syncthreads();
    if (t < 64) {
        float r = s_part[0][t] + s_part[1][t] + s_part[2][t] + s_part[3][t] + fc2_b[0];
        out[blockIdx.x * 64 + t] = r;
    }
}

extern "C" void kernel_launch(void* const* d_in, const int* in_sizes, int n_in,
                              void* d_out, int out_size, void* d_ws, size_t ws_size,
                              hipStream_t stream)
{
    const float* x       = (const float*)d_in[0];
    const float* tg      = (const float*)d_in[1];
    const float* fc0_w   = (const float*)d_in[2];
    const float* fc0_b   = (const float*)d_in[3];
    const float* pole_re = (const float*)d_in[4];
    const float* pole_im = (const float*)d_in[5];
    const float* res_re  = (const float*)d_in[6];
    const float* res_im  = (const float*)d_in[7];
    const float* spec_re = (const float*)d_in[8];
    const float* spec_im = (const float*)d_in[9];
    const float* conv_w  = (const float*)d_in[10];
    const float* conv_b  = (const float*)d_in[11];
    const float* fc1_w   = (const float*)d_in[12];
    const float* fc1_b   = (const float*)d_in[13];
    const float* fc2_w   = (const float*)d_in[14];
    const float* fc2_b   = (const float*)d_in[15];
    float* out = (float*)d_out;

    char* ws = (char*)d_ws;
    const size_t plane = (size_t)(BB * WW) * AST * sizeof(float2);   // 2.11 MiB
    float2* alphaA = (float2*)ws;
    float2* alphaB = (float2*)(ws + plane);
    float2* hbuf   = (float2*)(ws + 2 * plane);                      // 2 MiB
    float2* Gbuf   = (float2*)(ws + 3 * plane);

    hipLaunchKernelGGL(k_genG_fc0, dim3(NLAYER * WW * WW / 4 + BB * WW), dim3(256), 0, stream,
                       pole_re, pole_im, res_re, res_im, spec_re, spec_im,
                       conv_w, tg, x, fc0_w, fc0_b, Gbuf, alphaA);
    float2* acur = alphaA;
    float2* anxt = alphaB;
    for (int layer = 0; layer < NLAYER; ++layer) {
        if (layer < NLAYER - 1)
            hipLaunchKernelGGL((k_apply_fft<false>), dim3(BB * WW), dim3(512), 0, stream,
                               acur, Gbuf, conv_b, anxt, (float2*)nullptr, layer);
        else
            hipLaunchKernelGGL((k_apply_fft<true>), dim3(BB * WW), dim3(512), 0, stream,
                               acur, Gbuf, conv_b, (float2*)nullptr, hbuf, layer);
        float2* tmp = acur; acur = anxt; anxt = tmp;
    }
    hipLaunchKernelGGL(k_head, dim3(BB * NFFT / 64), dim3(256), 0, stream,
                       (const float*)hbuf, fc1_w, fc1_b, fc2_w, fc2_b, out);
}

// Round 11
// 90.751 us; speedup vs baseline: 4.9600x; 1.1679x over previous
//
#include <hip/hip_runtime.h>
#include <math.h>

#define NFFT   2048
#define M2     1024
#define LOG2N  11
#define BB     8
#define WW     32
#define MM     16
#define NLAYER 4
#define AST    1032      // row stride (float2) for alpha / G half-spectra

// Padded LDS index (element-granular) for 1024-pt FFT arrays
#define PAD(i) ((i) + ((i) >> 5))
#define PADDED_M (M2 + (M2 >> 5))   // 1056

// ---------- fast gelu (exact-erf form, A&S 7.1.26, |err| <= 1.5e-7) ----------
__device__ __forceinline__ float gelu_f(float v) {
    float ax = fabsf(v) * 0.70710678118654752440f;
    float t  = __builtin_amdgcn_rcpf(fmaf(0.3275911f, ax, 1.0f));
    float s  = fmaf(1.061405429f, t, -1.453152027f);
    s = fmaf(s, t, 1.421413741f);
    s = fmaf(s, t, -0.284496736f);
    s = fmaf(s, t, 0.254829592f);
    s = s * t;
    float e  = __expf(-ax * ax);
    float er = fmaf(-s, e, 1.0f);          // erf(|v|/sqrt2)
    er = copysignf(er, v);
    return 0.5f * v * (1.0f + er);
}

// ---------- complex helpers ----------
__device__ __forceinline__ float2 cadd(float2 a, float2 b) { return make_float2(a.x + b.x, a.y + b.y); }
__device__ __forceinline__ float2 csub(float2 a, float2 b) { return make_float2(a.x - b.x, a.y - b.y); }
__device__ __forceinline__ float2 cmul(float2 a, float2 b) {
    return make_float2(fmaf(a.x, b.x, -a.y * b.y), fmaf(a.x, b.y, a.y * b.x));
}
template<int S> __device__ __forceinline__ float2 caddi(float2 a, float2 b) {
    return (S > 0) ? make_float2(a.x - b.y, a.y + b.x) : make_float2(a.x + b.y, a.y - b.x);
}
template<int S> __device__ __forceinline__ float2 csubi(float2 a, float2 b) {
    return (S > 0) ? make_float2(a.x + b.y, a.y - b.x) : make_float2(a.x - b.y, a.y + b.x);
}

template<int S> __device__ __forceinline__ void dft4(float2* a) {
    float2 t0 = cadd(a[0], a[2]), t1 = csub(a[0], a[2]);
    float2 t2 = cadd(a[1], a[3]), t3 = csub(a[1], a[3]);
    a[0] = cadd(t0, t2);
    a[2] = csub(t0, t2);
    a[1] = caddi<S>(t1, t3);
    a[3] = csubi<S>(t1, t3);
}

// ---------- Stockham radix-4 pass on float2 LDS, reg twiddle w1 ----------
// w1f is the FORWARD twiddle (cos, -sin) for this thread's s; S>0 conjugates.
template<int LS, int S>
__device__ __forceinline__ void pass_cx(const float2* src, float2* dst, int t, float2 w1f) {
    float2 a[4];
    #pragma unroll
    for (int r = 0; r < 4; ++r) a[r] = src[PAD(t + r * 256)];
    if (LS > 1) {
        float2 w1 = (S > 0) ? make_float2(w1f.x, -w1f.y) : w1f;
        float2 w2 = cmul(w1, w1);
        float2 w3 = cmul(w2, w1);
        a[1] = cmul(a[1], w1);
        a[2] = cmul(a[2], w2);
        a[3] = cmul(a[3], w3);
    }
    dft4<S>(a);
    int s = t & (LS - 1);
    int base = (t / LS) * (4 * LS) + s;
    #pragma unroll
    for (int r = 0; r < 4; ++r) dst[PAD(base + r * LS)] = a[r];
}

// Forward twiddles for the 4 twiddled passes, computed once per thread (t<256).
struct Tw { float2 t4, t16, t64, t256; };
__device__ __forceinline__ Tw make_tw(int t) {
    Tw w;
    float sn, cs;
    const float c0 = 6.2831853071795864769f;
    __sincosf(c0 * (float)(t & 3)   * (1.0f / 16.0f),   &sn, &cs); w.t4   = make_float2(cs, -sn);
    __sincosf(c0 * (float)(t & 15)  * (1.0f / 64.0f),   &sn, &cs); w.t16  = make_float2(cs, -sn);
    __sincosf(c0 * (float)(t & 63)  * (1.0f / 256.0f),  &sn, &cs); w.t64  = make_float2(cs, -sn);
    __sincosf(c0 * (float)(t & 255) * (1.0f / 1024.0f), &sn, &cs); w.t256 = make_float2(cs, -sn);
    return w;
}

// 1024-pt FFT: input natural order in A, output in B. act = (t < 256).
// Caller must __syncthreads() before calling.
template<int S>
__device__ __forceinline__ void fft1024_cx(float2* A, float2* B, int t, bool act, const Tw& w) {
    if (act) pass_cx<1,   S>(A, B, t, make_float2(1.0f, 0.0f));
    __syncthreads();
    if (act) pass_cx<4,   S>(B, A, t, w.t4);
    __syncthreads();
    if (act) pass_cx<16,  S>(A, B, t, w.t16);
    __syncthreads();
    if (act) pass_cx<64,  S>(B, A, t, w.t64);
    __syncthreads();
    if (act) pass_cx<256, S>(A, B, t, w.t256);
    __syncthreads();
}

// ---------- K_genG_fc0 ----------
// Blocks 0..1023: genG, wave-per-unit. unit u = blk*4 + wave; (l,o,i) from u.
// Each lane owns 16 bins k = lane + 64j. Modes outer, bins inner; imag
// accumulator defers the *omega to the end. Lane 0 handles Nyquist + DC.
// Blocks 1024..1279: fc0 + rfft for row = blk-1024.
__global__ __launch_bounds__(256) void k_genG_fc0(
    const float* __restrict__ pole_re, const float* __restrict__ pole_im,
    const float* __restrict__ res_re,  const float* __restrict__ res_im,
    const float* __restrict__ spec_re, const float* __restrict__ spec_im,
    const float* __restrict__ conv_w,  const float* __restrict__ tgrid,
    const float* __restrict__ x,       const float* __restrict__ fc0_w,
    const float* __restrict__ fc0_b,
    float2* __restrict__ G, float2* __restrict__ alpha)
{
    __shared__ float2 Acx[PADDED_M], Bcx[PADDED_M];
    int t = threadIdx.x;
    int blk = blockIdx.x;
    float dt = tgrid[1] - tgrid[0];
    float fscale = 6.2831853071795864769f / ((float)NFFT * dt);

    if (blk < NLAYER * WW * WW / 4) {
        // ---- genG: one (l,o,i) unit per wave ----
        int lane = t & 63;
        int u = blk * 4 + (t >> 6);
        int l = u >> 10, r = u & 1023, o = r >> 5, i = r & 31;
        int pb = ((l * WW + i) * WW + o) * MM;
        float cw = conv_w[(l * WW + o) * WW + i];
        float w2r[16];
        float2 acc[16];
        #pragma unroll
        for (int j = 0; j < 16; ++j) {
            float wv = fscale * (float)(lane + 64 * j);
            w2r[j] = wv * wv;
            acc[j] = make_float2(cw, 0.0f);
        }
        #pragma unroll
        for (int mq = 0; mq < 4; ++mq) {
            float4 P_re = *(const float4*)&pole_re[pb + 4 * mq];
            float4 P_im = *(const float4*)&pole_im[pb + 4 * mq];
            float4 R_re = *(const float4*)&res_re [pb + 4 * mq];
            float4 R_im = *(const float4*)&res_im [pb + 4 * mq];
            #pragma unroll
            for (int mm = 0; mm < 4; ++mm) {
                float Rp = (&P_re.x)[mm], Ip = (&P_im.x)[mm];
                float Rr = (&R_re.x)[mm], Ir = (&R_im.x)[mm];
                float b   = fmaf(Rr, Rp, Ir * Ip);      // Re(r * conj(p))
                float c   = fmaf(Rp, Rp, Ip * Ip);      // |p|^2
                float dd  = 2.0f * Rp;
                float dd2 = dd * dd;
                float add = Rr * dd;
                float bdd = b * dd;
                #pragma unroll
                for (int j = 0; j < 16; ++j) {
                    float uu  = c - w2r[j];
                    float inv = __builtin_amdgcn_rcpf(fmaf(dd2, w2r[j], uu * uu));
                    acc[j].x = fmaf(fmaf(add, w2r[j], b * uu), -inv, acc[j].x);
                    acc[j].y = fmaf(fmaf(Rr, uu, -bdd), inv, acc[j].y);  // *wv deferred
                }
            }
        }
        #pragma unroll
        for (int j = 0; j < 16; ++j)
            acc[j].y *= fscale * (float)(lane + 64 * j);
        if (lane < MM) {               // spectral-conv fold: bins k = lane < 16
            if (lane) {
                acc[0].x += spec_re[pb + lane];
                acc[0].y += spec_im[pb + lane];
            } else {
                acc[0].x += spec_re[pb];   // DC stays real
            }
        }
        float2* grow = G + (size_t)((l * WW + o) * WW + i) * AST;
        #pragma unroll
        for (int j = 0; j < 16; ++j) grow[lane + 64 * j] = acc[j];
        if (lane == 0) {               // Nyquist: Re(H(w_nyq)), w negative
            float wn = -fscale * (float)M2;
            float accn = cw;
            #pragma unroll
            for (int mq = 0; mq < 4; ++mq) {
                float4 P_re = *(const float4*)&pole_re[pb + 4 * mq];
                float4 P_im = *(const float4*)&pole_im[pb + 4 * mq];
                float4 R_re = *(const float4*)&res_re [pb + 4 * mq];
                float4 R_im = *(const float4*)&res_im [pb + 4 * mq];
                #pragma unroll
                for (int mm = 0; mm < 4; ++mm) {
                    float Rp = (&P_re.x)[mm], Ip = (&P_im.x)[mm];
                    float Rr = (&R_re.x)[mm], Ir = (&R_im.x)[mm];
                    float e   = wn - Ip;
                    float num = fmaf(Ir, e, -(Rr * Rp));
                    float den = fmaf(e, e, Rp * Rp);
                    accn += num * __builtin_amdgcn_rcpf(den);
                }
            }
            grow[M2] = make_float2(accn, 0.0f);
        }
    } else {
        // ---- fc0 + rfft path ----
        int row = blk - NLAYER * WW * WW / 4;   // b*32 + w
        int b = row >> 5, w = row & 31;
        float w0 = fc0_w[2 * w], w1 = fc0_w[2 * w + 1], b0 = fc0_b[w];
        Tw tw = make_tw(t);
        const float2* x2 = (const float2*)(x + (size_t)b * NFFT);
        #pragma unroll
        for (int j = 0; j < 4; ++j) {
            int n = t + j * 256;
            float2 xv = x2[n];
            float g0 = (float)(2 * n)     * (1.0f / 2047.0f);
            float g1 = (float)(2 * n + 1) * (1.0f / 2047.0f);
            float v0 = gelu_f(fmaf(w0, xv.x, fmaf(w1, g0, b0)));
            float v1 = gelu_f(fmaf(w0, xv.y, fmaf(w1, g1, b0)));
            Acx[PAD(n)] = make_float2(v0, v1);   // z[n] = h[2n] + i h[2n+1]
        }
        __syncthreads();
        fft1024_cx<-1>(Acx, Bcx, t, true, tw);
        float2* arow = alpha + (size_t)row * AST;
        #pragma unroll
        for (int j = 0; j < 4; ++j) {
            int k  = t + j * 256;
            int mk = (M2 - k) & (M2 - 1);
            float2 Zk  = Bcx[PAD(k)];
            float2 Zmk = Bcx[PAD(mk)];
            float2 A  = make_float2(0.5f * (Zk.x + Zmk.x), 0.5f * (Zk.y - Zmk.y));
            float2 Bv = make_float2(0.5f * (Zk.y + Zmk.y), -0.5f * (Zk.x - Zmk.x));
            float ph = (3.1415926535897932385f / (float)M2) * (float)k;
            float sn, cs;
            __sincosf(ph, &sn, &cs);
            float2 e = make_float2(cs, -sn);           // e^{-i*2pi*k/N}
            float2 X = cadd(A, cmul(Bv, e));
            arow[k] = X;
            if (k == 0) arow[M2] = make_float2(A.x - Bv.x, 0.0f);
        }
    }
}

// ---------- K_layer: einsum over i + irfft + gelu + (rfft | store h) ----------
// block = (b,o) row, 512 threads. Yh[k] = sum_i alpha[b,i,k]*G[l,o,i,k]
template<bool LAST>
__global__ __launch_bounds__(512) void k_apply_fft(
    const float2* __restrict__ alpha, const float2* __restrict__ G,
    const float* __restrict__ conv_b, float2* __restrict__ alpha_next,
    float2* __restrict__ hout, int layer)
{
    __shared__ __align__(16) float2 Ycx[M2 + 2];
    __shared__ float2 Acx[PADDED_M], Bcx[PADDED_M];
    int t = threadIdx.x;
    int row = blockIdx.x;            // b*32 + o
    int b = row >> 5, o = row & 31;
    const float2* abase = alpha + (size_t)(b * WW) * AST;
    const float2* gbase = G + (size_t)((layer * WW + o) * WW) * AST;
    Tw tw;
    if (t < 256) tw = make_tw(t);

    // einsum: thread t owns bins 2t, 2t+1 -> float4 loads (16B)
    float2 acc0 = make_float2(0.0f, 0.0f);
    float2 acc1 = make_float2(0.0f, 0.0f);
    #pragma unroll 4
    for (int i = 0; i < 32; ++i) {
        const float4* ar = (const float4*)(abase + (size_t)i * AST);
        const float4* gr = (const float4*)(gbase + (size_t)i * AST);
        float4 av = ar[t];
        float4 gv = gr[t];
        acc0.x = fmaf(av.x, gv.x, fmaf(-av.y, gv.y, acc0.x));
        acc0.y = fmaf(av.x, gv.y, fmaf( av.y, gv.x, acc0.y));
        acc1.x = fmaf(av.z, gv.z, fmaf(-av.w, gv.w, acc1.x));
        acc1.y = fmaf(av.z, gv.w, fmaf( av.w, gv.z, acc1.y));
    }
    // Nyquist: real dot over i, wave-0 shuffle reduce
    if (t < 64) {
        float p = 0.0f;
        if (t < 32)
            p = abase[(size_t)t * AST + M2].x * gbase[(size_t)t * AST + M2].x;
        #pragma unroll
        for (int off = 16; off >= 1; off >>= 1) p += __shfl_xor(p, off);
        if (t == 0) Ycx[M2] = make_float2(p, 0.0f);
    }
    if (t == 0) acc0.x += (float)NFFT * conv_b[layer * WW + o];
    ((float4*)Ycx)[t] = make_float4(acc0.x, acc0.y, acc1.x, acc1.y);
    __syncthreads();

    // irfft pack: Z[k] = A + iB from X[k], X[M2-k]
    #pragma unroll
    for (int j = 0; j < 2; ++j) {
        int k = t + j * 512;
        float2 Xk = Ycx[k];
        float2 Xm = Ycx[M2 - k];
        float2 A = make_float2(0.5f * (Xk.x + Xm.x), 0.5f * (Xk.y - Xm.y));
        float2 u = make_float2(Xk.x - Xm.x, Xk.y + Xm.y);
        float ph = (3.1415926535897932385f / (float)M2) * (float)k;
        float sn, cs;
        __sincosf(ph, &sn, &cs);
        float2 e = make_float2(cs, sn);            // e^{+i*2pi*k/N}
        float2 Bv = cmul(u, e);
        Acx[PAD(k)] = make_float2(A.x - 0.5f * Bv.y, A.y + 0.5f * Bv.x);
    }
    __syncthreads();
    fft1024_cx<1>(Acx, Bcx, t, t < 256, tw);      // inverse -> B
    const float invM = 1.0f / (float)M2;
    if (LAST) {
        #pragma unroll
        for (int j = 0; j < 2; ++j) {
            int n = t + j * 512;
            float2 z = Bcx[PAD(n)];
            hout[(size_t)row * M2 + n] = make_float2(gelu_f(z.x * invM), gelu_f(z.y * invM));
        }
    } else {
        #pragma unroll
        for (int j = 0; j < 2; ++j) {
            int n = t + j * 512;
            float2 z = Bcx[PAD(n)];
            Acx[PAD(n)] = make_float2(gelu_f(z.x * invM), gelu_f(z.y * invM));
        }
        __syncthreads();
        fft1024_cx<-1>(Acx, Bcx, t, t < 256, tw);
        float2* arow = alpha_next + (size_t)row * AST;
        #pragma unroll
        for (int j = 0; j < 2; ++j) {
            int k  = t + j * 512;
            int mk = (M2 - k) & (M2 - 1);
            float2 Zk  = Bcx[PAD(k)];
            float2 Zmk = Bcx[PAD(mk)];
            float2 A  = make_float2(0.5f * (Zk.x + Zmk.x), 0.5f * (Zk.y - Zmk.y));
            float2 Bv = make_float2(0.5f * (Zk.y + Zmk.y), -0.5f * (Zk.x - Zmk.x));
            float ph = (3.1415926535897932385f / (float)M2) * (float)k;
            float sn, cs;
            __sincosf(ph, &sn, &cs);
            float2 e = make_float2(cs, -sn);       // e^{-i*2pi*k/N}
            float2 X = cadd(A, cmul(Bv, e));
            arow[k] = X;
            if (k == 0) arow[M2] = make_float2(A.x - Bv.x, 0.0f);
        }
    }
}

// ---------- K5: head ----------
__global__ __launch_bounds__(256) void k_head(
    const float* __restrict__ h, const float* __restrict__ fc1_w,
    const float* __restrict__ fc1_b, const float* __restrict__ fc2_w,
    const float* __restrict__ fc2_b, float* __restrict__ out)
{
    __shared__ float s_w1[128 * 32];
    __shared__ float s_b1[128];
    __shared__ float s_w2[128];
    __shared__ float s_part[4][64];
    int t = threadIdx.x;
    for (int j = t; j < 128 * 32; j += 256) s_w1[j] = fc1_w[j];
    if (t < 128) { s_b1[t] = fc1_b[t]; s_w2[t] = fc2_w[t]; }
    __syncthreads();
    int wv  = t >> 6;                       // wave id = n-group
    int ln  = t & 63;
    int pos = blockIdx.x * 64 + ln;         // b*2048 + l
    int b = pos >> LOG2N, l = pos & (NFFT - 1);
    float hreg[32];
    #pragma unroll
    for (int w = 0; w < 32; ++w) hreg[w] = h[(b * WW + w) * NFFT + l];
    float acc = 0.0f;
    int n0 = wv * 32;
    for (int n = n0; n < n0 + 32; ++n) {
        float a = s_b1[n];
        #pragma unroll
        for (int w = 0; w < 32; w += 4) {
            float4 ww = *(const float4*)&s_w1[n * 32 + w];
            a = fmaf(ww.x, hreg[w],     a);
            a = fmaf(ww.y, hreg[w + 1], a);
            a = fmaf(ww.z, hreg[w + 2], a);
            a = fmaf(ww.w, hreg[w + 3], a);
        }
        acc = fmaf(s_w2[n], gelu_f(a), acc);
    }
    s_part[wv][ln] = acc;
    __syncthreads();
    if (t < 64) {
        float r = s_part[0][t] + s_part[1][t] + s_part[2][t] + s_part[3][t] + fc2_b[0];
        out[blockIdx.x * 64 + t] = r;
    }
}

extern "C" void kernel_launch(void* const* d_in, const int* in_sizes, int n_in,
                              void* d_out, int out_size, void* d_ws, size_t ws_size,
                              hipStream_t stream)
{
    const float* x       = (const float*)d_in[0];
    const float* tg      = (const float*)d_in[1];
    const float* fc0_w   = (const float*)d_in[2];
    const float* fc0_b   = (const float*)d_in[3];
    const float* pole_re = (const float*)d_in[4];
    const float* pole_im = (const float*)d_in[5];
    const float* res_re  = (const float*)d_in[6];
    const float* res_im  = (const float*)d_in[7];
    const float* spec_re = (const float*)d_in[8];
    const float* spec_im = (const float*)d_in[9];
    const float* conv_w  = (const float*)d_in[10];
    const float* conv_b  = (const float*)d_in[11];
    const float* fc1_w   = (const float*)d_in[12];
    const float* fc1_b   = (const float*)d_in[13];
    const float* fc2_w   = (const float*)d_in[14];
    const float* fc2_b   = (const float*)d_in[15];
    float* out = (float*)d_out;

    char* ws = (char*)d_ws;
    const size_t plane = (size_t)(BB * WW) * AST * sizeof(float2);   // 2.11 MiB
    float2* alphaA = (float2*)ws;
    float2* alphaB = (float2*)(ws + plane);
    float2* hbuf   = (float2*)(ws + 2 * plane);                      // 2 MiB
    float2* Gbuf   = (float2*)(ws + 3 * plane);

    hipLaunchKernelGGL(k_genG_fc0, dim3(NLAYER * WW * WW / 4 + BB * WW), dim3(256), 0, stream,
                       pole_re, pole_im, res_re, res_im, spec_re, spec_im,
                       conv_w, tg, x, fc0_w, fc0_b, Gbuf, alphaA);
    float2* acur = alphaA;
    float2* anxt = alphaB;
    for (int layer = 0; layer < NLAYER; ++layer) {
        if (layer < NLAYER - 1)
            hipLaunchKernelGGL((k_apply_fft<false>), dim3(BB * WW), dim3(512), 0, stream,
                               acur, Gbuf, conv_b, anxt, (float2*)nullptr, layer);
        else
            hipLaunchKernelGGL((k_apply_fft<true>), dim3(BB * WW), dim3(512), 0, stream,
                               acur, Gbuf, conv_b, (float2*)nullptr, hbuf, layer);
        float2* tmp = acur; acur = anxt; anxt = tmp;
    }
    hipLaunchKernelGGL(k_head, dim3(BB * NFFT / 64), dim3(256), 0, stream,
                       (const float*)hbuf, fc1_w, fc1_b, fc2_w, fc2_b, out);
}